// Round 7
// baseline (225.597 us; speedup 1.0000x reference)
//
#include <hip/hip_runtime.h>
#include <hip/hip_bf16.h>
#include <math.h>

#define F_IN 128
#define HID  16
#define NCLS 10
#define BS   1024                // nodes per bucket (pow2)
#define CH   8192                // edges per binning chunk
#define KPL  8                   // chunks per lane in column scan (<=512 chunks)

typedef unsigned int uint;
typedef unsigned short ushort;

// ---------- chunk x bucket histogram matrix ----------
__global__ void k_hist2(const int* __restrict__ col, int* __restrict__ hist, int E, int nbv) {
    extern __shared__ int h[];
    int t = threadIdx.x, k = blockIdx.x;
    for (int i = t; i < nbv; i += 256) h[i] = 0;
    __syncthreads();
    int start = k * CH, end = min(start + CH, E);
    for (int i = start + t; i < end; i += 256) atomicAdd(&h[col[i] >> 10], 1);
    __syncthreads();
    for (int i = t; i < nbv; i += 256) hist[(size_t)k * nbv + i] = h[i];
}

// ---------- fused: column scan across chunks (per bucket) + bucket-offset scan ----------
__global__ __launch_bounds__(1024) void k_cb(int* __restrict__ hist, int* __restrict__ boff,
                                             int nchunk, int nbv, int E) {
    __shared__ int tot[128];
    int wave = threadIdx.x >> 6, lane = threadIdx.x & 63;
    for (int b = wave; b < nbv; b += 16) {
        int vals[KPL];
        int ls = 0;
        #pragma unroll
        for (int i = 0; i < KPL; ++i) {
            int k = lane * KPL + i;
            vals[i] = (k < nchunk) ? hist[(size_t)k * nbv + b] : 0;
            ls += vals[i];
        }
        int inc = ls;
        #pragma unroll
        for (int d = 1; d < 64; d <<= 1) {
            int v = __shfl_up(inc, d, 64);
            if (lane >= d) inc += v;
        }
        int run = inc - ls;
        #pragma unroll
        for (int i = 0; i < KPL; ++i) {
            int k = lane * KPL + i;
            if (k < nchunk) { hist[(size_t)k * nbv + b] = run; run += vals[i]; }
        }
        if (lane == 63) tot[b] = inc;
    }
    __syncthreads();
    if (threadIdx.x == 0) {
        int run = 0;
        for (int b = 0; b < nbv; ++b) { boff[b] = run; run += tot[b]; }
        boff[nbv] = E;
    }
}

// ---------- bin: place edges via precomputed bases + LDS cursors ----------
__global__ void k_binW(const int* __restrict__ row, const int* __restrict__ col,
                       const int* __restrict__ hist, const int* __restrict__ boff,
                       uint* __restrict__ pairs, int E, int nbv) {
    extern __shared__ int lds[];          // gbase | cur
    int* gbase = lds;
    int* cur   = lds + nbv;
    int t = threadIdx.x, k = blockIdx.x;
    for (int i = t; i < nbv; i += 256) {
        gbase[i] = boff[i] + hist[(size_t)k * nbv + i];
        cur[i] = 0;
    }
    __syncthreads();
    int start = k * CH, end = min(start + CH, E);
    for (int i = start + t; i < end; i += 256) {
        int c = col[i];
        int b = c >> 10;
        int rk = atomicAdd(&cur[b], 1);
        pairs[gbase[b] + rk] = ((uint)row[i] << 10) | (uint)(c & (BS - 1));
    }
}

// ---------- per-node count + in-bucket scan -> off, dinv ----------
__global__ __launch_bounds__(1024) void k_nscan(const uint* __restrict__ pairs,
                                                const int* __restrict__ boff,
                                                int* __restrict__ off, float* __restrict__ dinv,
                                                int N, int nbv, int E) {
    __shared__ int c[BS];
    __shared__ int s[BS];
    int b = blockIdx.x, t = threadIdx.x;
    c[t] = 0;
    __syncthreads();
    int st = boff[b], en = boff[b + 1];
    for (int i = st + t; i < en; i += 1024) atomicAdd(&c[pairs[i] & (BS - 1)], 1);
    __syncthreads();
    int v = c[t];
    s[t] = v;
    __syncthreads();
    for (int ofs = 1; ofs < 1024; ofs <<= 1) {
        int val = (t >= ofs) ? s[t - ofs] : 0;
        __syncthreads();
        if (t >= ofs) s[t] += val;
        __syncthreads();
    }
    int n = (b << 10) + t;
    if (n < N) {
        off[n] = st + s[t] - v;
        dinv[n] = rsqrtf((float)v + 1.0f);
    }
    if (b == nbv - 1 && t == 0) off[N] = E;
}

// ---------- place: per bucket, LDS cursors -> srow ----------
__global__ __launch_bounds__(1024) void k_place(const uint* __restrict__ pairs,
                                                const int* __restrict__ boff,
                                                const int* __restrict__ off,
                                                int* __restrict__ srow, int N) {
    __shared__ int so[BS];
    __shared__ int cu[BS];
    int b = blockIdx.x, t = threadIdx.x;
    int n = (b << 10) + t;
    so[t] = (n < N) ? off[n] : 0;
    cu[t] = 0;
    __syncthreads();
    int st = boff[b], en = boff[b + 1];
    for (int i = st + t; i < en; i += 1024) {
        uint v = pairs[i];
        int cl = v & (BS - 1);
        int p = so[cl] + atomicAdd(&cu[cl], 1);
        srow[p] = (int)(v >> 10);
    }
}

// ---------- xw_s = dinv[n] * (x @ W1), stored bf16 (3.2MB: fits per-XCD L2) ----------
__global__ void k_xw(const float* __restrict__ x, const float* __restrict__ W1,
                     const float* __restrict__ dinv, __hip_bfloat16* __restrict__ xws, int N) {
    __shared__ float Ws[F_IN * HID];
    __shared__ float xs[16 * (F_IN + 1)];
    int t = threadIdx.x;
    for (int i = t; i < F_IN * HID; i += 256) Ws[i] = W1[i];
    int base = blockIdx.x * 16;
    for (int i = t; i < 16 * F_IN; i += 256) {
        int n = i >> 7, k = i & (F_IN - 1);
        xs[n * (F_IN + 1) + k] = (base + n < N) ? x[(size_t)(base + n) * F_IN + k] : 0.f;
    }
    __syncthreads();
    int n = t >> 4, h = t & 15;
    if (base + n >= N) return;
    const float* xr = xs + n * (F_IN + 1);
    float acc = 0.f;
    #pragma unroll
    for (int k = 0; k < F_IN; ++k) acc += xr[k] * Ws[k * HID + h];
    xws[(size_t)(base + n) * HID + h] = __float2bfloat16(dinv[base + n] * acc);
}

// ---------- layer-1 pull: hs = bf16(dinv * relu(dinv*sum + b1)) ----------
__global__ void k_agg1(const __hip_bfloat16* __restrict__ xws, const int* __restrict__ off,
                       const int* __restrict__ srow, const float* __restrict__ dinv,
                       const float* __restrict__ b1, __hip_bfloat16* __restrict__ hs, int N) {
    int n = (blockIdx.x * blockDim.x + threadIdx.x) >> 4;
    int l = threadIdx.x & 15;
    if (n >= N) return;
    int s = off[n], e = off[n + 1];
    float a0 = __bfloat162float(xws[(size_t)n * HID + l]);   // self loop
    float a1 = 0.f, a2 = 0.f, a3 = 0.f;
    int i = s;
    for (; i + 7 < e; i += 8) {
        int r0 = srow[i],     r1 = srow[i + 1], r2 = srow[i + 2], r3 = srow[i + 3];
        int r4 = srow[i + 4], r5 = srow[i + 5], r6 = srow[i + 6], r7 = srow[i + 7];
        a0 += __bfloat162float(xws[(size_t)r0 * HID + l]);
        a1 += __bfloat162float(xws[(size_t)r1 * HID + l]);
        a2 += __bfloat162float(xws[(size_t)r2 * HID + l]);
        a3 += __bfloat162float(xws[(size_t)r3 * HID + l]);
        a0 += __bfloat162float(xws[(size_t)r4 * HID + l]);
        a1 += __bfloat162float(xws[(size_t)r5 * HID + l]);
        a2 += __bfloat162float(xws[(size_t)r6 * HID + l]);
        a3 += __bfloat162float(xws[(size_t)r7 * HID + l]);
    }
    for (; i < e; ++i) a0 += __bfloat162float(xws[(size_t)srow[i] * HID + l]);
    float acc = (a0 + a1) + (a2 + a3);
    float d = dinv[n];
    float h = d * acc + b1[l];
    h = h > 0.f ? h : 0.f;
    hs[(size_t)n * HID + l] = __float2bfloat16(d * h);
}

// ---------- layer-2 pull + fused W2/b2/log_softmax ----------
__global__ void k_agg2(const __hip_bfloat16* __restrict__ hs, const int* __restrict__ off,
                       const int* __restrict__ srow, const float* __restrict__ dinv,
                       const float* __restrict__ W2, const float* __restrict__ b2,
                       float* __restrict__ out, int N) {
    __shared__ float gs[16][17];
    __shared__ float W2s[HID * NCLS];
    __shared__ float b2s[NCLS];
    int t = threadIdx.x;
    if (t < HID * NCLS) W2s[t] = W2[t];
    if (t < NCLS) b2s[t] = b2[t];
    int grp = t >> 4, l = t & 15;
    int n = blockIdx.x * 16 + grp;
    float g = 0.f;
    if (n < N) {
        int s = off[n], e = off[n + 1];
        float a0 = __bfloat162float(hs[(size_t)n * HID + l]);
        float a1 = 0.f, a2 = 0.f, a3 = 0.f;
        int i = s;
        for (; i + 7 < e; i += 8) {
            int r0 = srow[i],     r1 = srow[i + 1], r2 = srow[i + 2], r3 = srow[i + 3];
            int r4 = srow[i + 4], r5 = srow[i + 5], r6 = srow[i + 6], r7 = srow[i + 7];
            a0 += __bfloat162float(hs[(size_t)r0 * HID + l]);
            a1 += __bfloat162float(hs[(size_t)r1 * HID + l]);
            a2 += __bfloat162float(hs[(size_t)r2 * HID + l]);
            a3 += __bfloat162float(hs[(size_t)r3 * HID + l]);
            a0 += __bfloat162float(hs[(size_t)r4 * HID + l]);
            a1 += __bfloat162float(hs[(size_t)r5 * HID + l]);
            a2 += __bfloat162float(hs[(size_t)r6 * HID + l]);
            a3 += __bfloat162float(hs[(size_t)r7 * HID + l]);
        }
        for (; i < e; ++i) a0 += __bfloat162float(hs[(size_t)srow[i] * HID + l]);
        g = dinv[n] * ((a0 + a1) + (a2 + a3));
    }
    gs[grp][l] = g;
    __syncthreads();
    if (t < 16) {
        int n2 = blockIdx.x * 16 + t;
        if (n2 < N) {
            float v[NCLS];
            float m = -INFINITY;
            #pragma unroll
            for (int c = 0; c < NCLS; ++c) {
                float a = b2s[c];
                #pragma unroll
                for (int j = 0; j < HID; ++j) a += gs[t][j] * W2s[j * NCLS + c];
                v[c] = a;
                m = fmaxf(m, a);
            }
            float ssum = 0.f;
            #pragma unroll
            for (int c = 0; c < NCLS; ++c) ssum += __expf(v[c] - m);
            float lse = m + __logf(ssum);
            #pragma unroll
            for (int c = 0; c < NCLS; ++c) out[(size_t)n2 * NCLS + c] = v[c] - lse;
        }
    }
}

extern "C" void kernel_launch(void* const* d_in, const int* in_sizes, int n_in,
                              void* d_out, int out_size, void* d_ws, size_t ws_size,
                              hipStream_t stream) {
    const float* x  = (const float*)d_in[0];
    const int*   ei = (const int*)d_in[1];
    const float* W1 = (const float*)d_in[2];
    const float* b1 = (const float*)d_in[3];
    const float* W2 = (const float*)d_in[4];
    const float* b2 = (const float*)d_in[5];
    float* out = (float*)d_out;

    const int N = in_sizes[0] / F_IN;        // 100000
    const int E = in_sizes[1] / 2;           // 3200000
    const int* row = ei;                     // source
    const int* col = ei + E;                 // target

    const int nbv = (N + BS - 1) / BS;       // 98 buckets
    const int nchunk = (E + CH - 1) / CH;    // 391 chunks (<= 64*KPL)

    char* ws = (char*)d_ws;
    auto alignup = [](size_t v) { return (v + 255) & ~(size_t)255; };
    size_t offb = 0;
    int*   hist = (int*)  (ws + offb); offb += alignup((size_t)nchunk * nbv * 4);  // ~153 KB
    int*   boff = (int*)  (ws + offb); offb += alignup((size_t)(nbv + 1) * 4);
    int*   off  = (int*)  (ws + offb); offb += alignup((size_t)(N + 1) * 4);
    float* dinv = (float*)(ws + offb); offb += alignup((size_t)N * 4);
    uint*  pairs= (uint*) (ws + offb); offb += alignup((size_t)E * 4);
    int*   srow = (int*)  (ws + offb); offb += alignup((size_t)E * 4);
    __hip_bfloat16* xws = (__hip_bfloat16*)(ws + offb); offb += alignup((size_t)N * HID * 2);
    __hip_bfloat16* hs  = (__hip_bfloat16*)(ws + offb); offb += alignup((size_t)N * HID * 2);
    (void)ws_size; (void)n_in; (void)out_size;

    size_t histB = (size_t)nbv * 4;

    k_hist2<<<nchunk, 256, histB,     stream>>>(col, hist, E, nbv);
    k_cb   <<<1, 1024, 0,             stream>>>(hist, boff, nchunk, nbv, E);
    k_binW <<<nchunk, 256, 2 * histB, stream>>>(row, col, hist, boff, pairs, E, nbv);
    k_nscan<<<nbv, 1024, 0,           stream>>>(pairs, boff, off, dinv, N, nbv, E);
    k_xw   <<<(N + 15) / 16, 256, 0,  stream>>>(x, W1, dinv, xws, N);
    k_place<<<nbv, 1024, 0,           stream>>>(pairs, boff, off, srow, N);
    k_agg1 <<<(N * HID + 255) / 256, 256, 0, stream>>>(xws, off, srow, dinv, b1, hs, N);
    k_agg2 <<<(N + 15) / 16, 256, 0,  stream>>>(hs, off, srow, dinv, W2, b2, out, N);
}

// Round 8
// 185.153 us; speedup vs baseline: 1.2184x; 1.2184x over previous
//
#include <hip/hip_runtime.h>
#include <hip/hip_bf16.h>
#include <math.h>

#define F_IN 128
#define HID  16
#define NCLS 10
#define BS   1024                // nodes per bucket (pow2)
#define CH   8192                // edges per binning chunk
#define KPL  8                   // chunks per lane in column scan (<=512 chunks)

typedef unsigned int uint;

// ---------- chunk x bucket histogram, stored bucket-major: hist[b * nchunk + k] ----------
__global__ void k_hist2(const int* __restrict__ col, int* __restrict__ hist,
                        int E, int nbv, int nchunk) {
    extern __shared__ int h[];
    int t = threadIdx.x, k = blockIdx.x;
    for (int i = t; i < nbv; i += 256) h[i] = 0;
    __syncthreads();
    int start = k * CH, end = min(start + CH, E);
    for (int i = start + t; i < end; i += 256) atomicAdd(&h[col[i] >> 10], 1);
    __syncthreads();
    for (int i = t; i < nbv; i += 256) hist[(size_t)i * nchunk + k] = h[i];
}

// ---------- column scan: one wave per bucket, contiguous reads ----------
__global__ void k_cscan(int* __restrict__ hist, int* __restrict__ bcnt, int nchunk, int nbv) {
    int wave = threadIdx.x >> 6, lane = threadIdx.x & 63;
    int b = blockIdx.x * 4 + wave;
    if (b >= nbv) return;
    int* hb = hist + (size_t)b * nchunk;
    int vals[KPL];
    int ls = 0;
    #pragma unroll
    for (int i = 0; i < KPL; ++i) {
        int k = lane * KPL + i;
        vals[i] = (k < nchunk) ? hb[k] : 0;
        ls += vals[i];
    }
    int inc = ls;
    #pragma unroll
    for (int d = 1; d < 64; d <<= 1) {
        int v = __shfl_up(inc, d, 64);
        if (lane >= d) inc += v;
    }
    int run = inc - ls;                      // exclusive base for this lane
    #pragma unroll
    for (int i = 0; i < KPL; ++i) {
        int k = lane * KPL + i;
        if (k < nchunk) { hb[k] = run; run += vals[i]; }
    }
    if (lane == 63) bcnt[b] = inc;           // bucket total
}

// ---------- scan bucket totals -> boff ----------
__global__ void k_bscan(const int* __restrict__ bcnt, int* __restrict__ boff, int nbv, int E) {
    __shared__ int s[128];
    int t = threadIdx.x;
    int v = (t < nbv) ? bcnt[t] : 0;
    s[t] = v;
    __syncthreads();
    for (int ofs = 1; ofs < 128; ofs <<= 1) {
        int val = (t >= ofs) ? s[t - ofs] : 0;
        __syncthreads();
        if (t >= ofs) s[t] += val;
        __syncthreads();
    }
    if (t < nbv) boff[t] = s[t] - v;
    if (t == nbv) boff[t] = E;
}

// ---------- bin: place edges via precomputed bases + LDS cursors ----------
__global__ void k_binW(const int* __restrict__ row, const int* __restrict__ col,
                       const int* __restrict__ hist, const int* __restrict__ boff,
                       uint* __restrict__ pairs, int E, int nbv, int nchunk) {
    extern __shared__ int lds[];          // gbase | cur
    int* gbase = lds;
    int* cur   = lds + nbv;
    int t = threadIdx.x, k = blockIdx.x;
    for (int i = t; i < nbv; i += 256) {
        gbase[i] = boff[i] + hist[(size_t)i * nchunk + k];
        cur[i] = 0;
    }
    __syncthreads();
    int start = k * CH, end = min(start + CH, E);
    for (int i = start + t; i < end; i += 256) {
        int c = col[i];
        int b = c >> 10;
        int rk = atomicAdd(&cur[b], 1);
        pairs[gbase[b] + rk] = ((uint)row[i] << 10) | (uint)(c & (BS - 1));
    }
}

// ---------- per-node count + in-bucket scan -> off, dinv ----------
__global__ __launch_bounds__(1024) void k_nscan(const uint* __restrict__ pairs,
                                                const int* __restrict__ boff,
                                                int* __restrict__ off, float* __restrict__ dinv,
                                                int N, int nbv, int E) {
    __shared__ int c[BS];
    __shared__ int s[BS];
    int b = blockIdx.x, t = threadIdx.x;
    c[t] = 0;
    __syncthreads();
    int st = boff[b], en = boff[b + 1];
    for (int i = st + t; i < en; i += 1024) atomicAdd(&c[pairs[i] & (BS - 1)], 1);
    __syncthreads();
    int v = c[t];
    s[t] = v;
    __syncthreads();
    for (int ofs = 1; ofs < 1024; ofs <<= 1) {
        int val = (t >= ofs) ? s[t - ofs] : 0;
        __syncthreads();
        if (t >= ofs) s[t] += val;
        __syncthreads();
    }
    int n = (b << 10) + t;
    if (n < N) {
        off[n] = st + s[t] - v;
        dinv[n] = rsqrtf((float)v + 1.0f);
    }
    if (b == nbv - 1 && t == 0) off[N] = E;
}

// ---------- place: per bucket, LDS cursors -> srow ----------
__global__ __launch_bounds__(1024) void k_place(const uint* __restrict__ pairs,
                                                const int* __restrict__ boff,
                                                const int* __restrict__ off,
                                                int* __restrict__ srow, int N) {
    __shared__ int so[BS];
    __shared__ int cu[BS];
    int b = blockIdx.x, t = threadIdx.x;
    int n = (b << 10) + t;
    so[t] = (n < N) ? off[n] : 0;
    cu[t] = 0;
    __syncthreads();
    int st = boff[b], en = boff[b + 1];
    for (int i = st + t; i < en; i += 1024) {
        uint v = pairs[i];
        int cl = v & (BS - 1);
        int p = so[cl] + atomicAdd(&cu[cl], 1);
        srow[p] = (int)(v >> 10);
    }
}

// ---------- xw_s = dinv[n] * (x @ W1), stored bf16 (3.2MB) ----------
__global__ void k_xw(const float* __restrict__ x, const float* __restrict__ W1,
                     const float* __restrict__ dinv, __hip_bfloat16* __restrict__ xws, int N) {
    __shared__ float Ws[F_IN * HID];
    __shared__ float xs[16 * (F_IN + 1)];
    int t = threadIdx.x;
    for (int i = t; i < F_IN * HID; i += 256) Ws[i] = W1[i];
    int base = blockIdx.x * 16;
    for (int i = t; i < 16 * F_IN; i += 256) {
        int n = i >> 7, k = i & (F_IN - 1);
        xs[n * (F_IN + 1) + k] = (base + n < N) ? x[(size_t)(base + n) * F_IN + k] : 0.f;
    }
    __syncthreads();
    int n = t >> 4, h = t & 15;
    if (base + n >= N) return;
    const float* xr = xs + n * (F_IN + 1);
    float acc = 0.f;
    #pragma unroll
    for (int k = 0; k < F_IN; ++k) acc += xr[k] * Ws[k * HID + h];
    xws[(size_t)(base + n) * HID + h] = __float2bfloat16(dinv[base + n] * acc);
}

// ---------- layer-1 pull: hs = bf16(dinv * relu(dinv*sum + b1)) ----------
__global__ void k_agg1(const __hip_bfloat16* __restrict__ xws, const int* __restrict__ off,
                       const int* __restrict__ srow, const float* __restrict__ dinv,
                       const float* __restrict__ b1, __hip_bfloat16* __restrict__ hs, int N) {
    int n = (blockIdx.x * blockDim.x + threadIdx.x) >> 4;
    int l = threadIdx.x & 15;
    if (n >= N) return;
    int s = off[n], e = off[n + 1];
    float a0 = __bfloat162float(xws[(size_t)n * HID + l]);   // self loop
    float a1 = 0.f, a2 = 0.f, a3 = 0.f;
    int i = s;
    for (; i + 7 < e; i += 8) {
        int r0 = srow[i],     r1 = srow[i + 1], r2 = srow[i + 2], r3 = srow[i + 3];
        int r4 = srow[i + 4], r5 = srow[i + 5], r6 = srow[i + 6], r7 = srow[i + 7];
        a0 += __bfloat162float(xws[(size_t)r0 * HID + l]);
        a1 += __bfloat162float(xws[(size_t)r1 * HID + l]);
        a2 += __bfloat162float(xws[(size_t)r2 * HID + l]);
        a3 += __bfloat162float(xws[(size_t)r3 * HID + l]);
        a0 += __bfloat162float(xws[(size_t)r4 * HID + l]);
        a1 += __bfloat162float(xws[(size_t)r5 * HID + l]);
        a2 += __bfloat162float(xws[(size_t)r6 * HID + l]);
        a3 += __bfloat162float(xws[(size_t)r7 * HID + l]);
    }
    for (; i < e; ++i) a0 += __bfloat162float(xws[(size_t)srow[i] * HID + l]);
    float acc = (a0 + a1) + (a2 + a3);
    float d = dinv[n];
    float h = d * acc + b1[l];
    h = h > 0.f ? h : 0.f;
    hs[(size_t)n * HID + l] = __float2bfloat16(d * h);
}

// ---------- layer-2 pull + fused W2/b2/log_softmax ----------
__global__ void k_agg2(const __hip_bfloat16* __restrict__ hs, const int* __restrict__ off,
                       const int* __restrict__ srow, const float* __restrict__ dinv,
                       const float* __restrict__ W2, const float* __restrict__ b2,
                       float* __restrict__ out, int N) {
    __shared__ float gs[16][17];
    __shared__ float W2s[HID * NCLS];
    __shared__ float b2s[NCLS];
    int t = threadIdx.x;
    if (t < HID * NCLS) W2s[t] = W2[t];
    if (t < NCLS) b2s[t] = b2[t];
    int grp = t >> 4, l = t & 15;
    int n = blockIdx.x * 16 + grp;
    float g = 0.f;
    if (n < N) {
        int s = off[n], e = off[n + 1];
        float a0 = __bfloat162float(hs[(size_t)n * HID + l]);
        float a1 = 0.f, a2 = 0.f, a3 = 0.f;
        int i = s;
        for (; i + 7 < e; i += 8) {
            int r0 = srow[i],     r1 = srow[i + 1], r2 = srow[i + 2], r3 = srow[i + 3];
            int r4 = srow[i + 4], r5 = srow[i + 5], r6 = srow[i + 6], r7 = srow[i + 7];
            a0 += __bfloat162float(hs[(size_t)r0 * HID + l]);
            a1 += __bfloat162float(hs[(size_t)r1 * HID + l]);
            a2 += __bfloat162float(hs[(size_t)r2 * HID + l]);
            a3 += __bfloat162float(hs[(size_t)r3 * HID + l]);
            a0 += __bfloat162float(hs[(size_t)r4 * HID + l]);
            a1 += __bfloat162float(hs[(size_t)r5 * HID + l]);
            a2 += __bfloat162float(hs[(size_t)r6 * HID + l]);
            a3 += __bfloat162float(hs[(size_t)r7 * HID + l]);
        }
        for (; i < e; ++i) a0 += __bfloat162float(hs[(size_t)srow[i] * HID + l]);
        g = dinv[n] * ((a0 + a1) + (a2 + a3));
    }
    gs[grp][l] = g;
    __syncthreads();
    if (t < 16) {
        int n2 = blockIdx.x * 16 + t;
        if (n2 < N) {
            float v[NCLS];
            float m = -INFINITY;
            #pragma unroll
            for (int c = 0; c < NCLS; ++c) {
                float a = b2s[c];
                #pragma unroll
                for (int j = 0; j < HID; ++j) a += gs[t][j] * W2s[j * NCLS + c];
                v[c] = a;
                m = fmaxf(m, a);
            }
            float ssum = 0.f;
            #pragma unroll
            for (int c = 0; c < NCLS; ++c) ssum += __expf(v[c] - m);
            float lse = m + __logf(ssum);
            #pragma unroll
            for (int c = 0; c < NCLS; ++c) out[(size_t)n2 * NCLS + c] = v[c] - lse;
        }
    }
}

extern "C" void kernel_launch(void* const* d_in, const int* in_sizes, int n_in,
                              void* d_out, int out_size, void* d_ws, size_t ws_size,
                              hipStream_t stream) {
    const float* x  = (const float*)d_in[0];
    const int*   ei = (const int*)d_in[1];
    const float* W1 = (const float*)d_in[2];
    const float* b1 = (const float*)d_in[3];
    const float* W2 = (const float*)d_in[4];
    const float* b2 = (const float*)d_in[5];
    float* out = (float*)d_out;

    const int N = in_sizes[0] / F_IN;        // 100000
    const int E = in_sizes[1] / 2;           // 3200000
    const int* row = ei;                     // source
    const int* col = ei + E;                 // target

    const int nbv = (N + BS - 1) / BS;       // 98 buckets (<=128 for k_bscan)
    const int nchunk = (E + CH - 1) / CH;    // 391 chunks (<= 64*KPL)

    char* ws = (char*)d_ws;
    auto alignup = [](size_t v) { return (v + 255) & ~(size_t)255; };
    size_t offb = 0;
    int*   hist = (int*)  (ws + offb); offb += alignup((size_t)nbv * nchunk * 4); // ~153 KB
    int*   bcnt = (int*)  (ws + offb); offb += alignup((size_t)(nbv + 1) * 4);
    int*   boff = (int*)  (ws + offb); offb += alignup((size_t)(nbv + 1) * 4);
    int*   off  = (int*)  (ws + offb); offb += alignup((size_t)(N + 1) * 4);
    float* dinv = (float*)(ws + offb); offb += alignup((size_t)N * 4);
    uint*  pairs= (uint*) (ws + offb); offb += alignup((size_t)E * 4);
    int*   srow = (int*)  (ws + offb); offb += alignup((size_t)E * 4);
    __hip_bfloat16* xws = (__hip_bfloat16*)(ws + offb); offb += alignup((size_t)N * HID * 2);
    __hip_bfloat16* hs  = (__hip_bfloat16*)(ws + offb); offb += alignup((size_t)N * HID * 2);
    (void)ws_size; (void)n_in; (void)out_size;

    size_t histB = (size_t)nbv * 4;

    k_hist2<<<nchunk, 256, histB,      stream>>>(col, hist, E, nbv, nchunk);
    k_cscan<<<(nbv + 3) / 4, 256, 0,   stream>>>(hist, bcnt, nchunk, nbv);
    k_bscan<<<1, 128, 0,               stream>>>(bcnt, boff, nbv, E);
    k_binW <<<nchunk, 256, 2 * histB,  stream>>>(row, col, hist, boff, pairs, E, nbv, nchunk);
    k_nscan<<<nbv, 1024, 0,            stream>>>(pairs, boff, off, dinv, N, nbv, E);
    k_xw   <<<(N + 15) / 16, 256, 0,   stream>>>(x, W1, dinv, xws, N);
    k_place<<<nbv, 1024, 0,            stream>>>(pairs, boff, off, srow, N);
    k_agg1 <<<(N * HID + 255) / 256, 256, 0, stream>>>(xws, off, srow, dinv, b1, hs, N);
    k_agg2 <<<(N + 15) / 16, 256, 0,   stream>>>(hs, off, srow, dinv, W2, b2, out, N);
}

// Round 9
// 167.547 us; speedup vs baseline: 1.3465x; 1.1051x over previous
//
#include <hip/hip_runtime.h>
#include <hip/hip_bf16.h>
#include <math.h>

#define F_IN 128
#define HID  16
#define NCLS 10
#define BS   1024                // nodes per bucket (pow2)
#define CH   8192                // edges per binning chunk
#define KPL  8                   // chunks per lane in column scan (<=512 chunks)

typedef unsigned int uint;
typedef __attribute__((ext_vector_type(8))) short short8v;
typedef __attribute__((ext_vector_type(4))) float f32x4;

static __device__ __forceinline__ short f2bf(float f) {
    __hip_bfloat16 h = __float2bfloat16(f);
    return *reinterpret_cast<short*>(&h);
}

// ---------- chunk x bucket histogram, bucket-major: hist[b * nchunk + k] ----------
__global__ void k_hist2(const int* __restrict__ col, int* __restrict__ hist,
                        int E, int nbv, int nchunk) {
    extern __shared__ int h[];
    int t = threadIdx.x, k = blockIdx.x;
    for (int i = t; i < nbv; i += 256) h[i] = 0;
    __syncthreads();
    int start = k * CH, end = min(start + CH, E);
    for (int i = start + t; i < end; i += 256) atomicAdd(&h[col[i] >> 10], 1);
    __syncthreads();
    for (int i = t; i < nbv; i += 256) hist[(size_t)i * nchunk + k] = h[i];
}

// ---------- column scan: one wave per bucket, contiguous reads ----------
__global__ void k_cscan(int* __restrict__ hist, int* __restrict__ bcnt, int nchunk, int nbv) {
    int wave = threadIdx.x >> 6, lane = threadIdx.x & 63;
    int b = blockIdx.x * 4 + wave;
    if (b >= nbv) return;
    int* hb = hist + (size_t)b * nchunk;
    int vals[KPL];
    int ls = 0;
    #pragma unroll
    for (int i = 0; i < KPL; ++i) {
        int k = lane * KPL + i;
        vals[i] = (k < nchunk) ? hb[k] : 0;
        ls += vals[i];
    }
    int inc = ls;
    #pragma unroll
    for (int d = 1; d < 64; d <<= 1) {
        int v = __shfl_up(inc, d, 64);
        if (lane >= d) inc += v;
    }
    int run = inc - ls;
    #pragma unroll
    for (int i = 0; i < KPL; ++i) {
        int k = lane * KPL + i;
        if (k < nchunk) { hb[k] = run; run += vals[i]; }
    }
    if (lane == 63) bcnt[b] = inc;
}

// ---------- scan bucket totals -> boff ----------
__global__ void k_bscan(const int* __restrict__ bcnt, int* __restrict__ boff, int nbv, int E) {
    __shared__ int s[128];
    int t = threadIdx.x;
    int v = (t < nbv) ? bcnt[t] : 0;
    s[t] = v;
    __syncthreads();
    for (int ofs = 1; ofs < 128; ofs <<= 1) {
        int val = (t >= ofs) ? s[t - ofs] : 0;
        __syncthreads();
        if (t >= ofs) s[t] += val;
        __syncthreads();
    }
    if (t < nbv) boff[t] = s[t] - v;
    if (t == nbv) boff[t] = E;
}

// ---------- bin: place edges via precomputed bases + LDS cursors ----------
__global__ void k_binW(const int* __restrict__ row, const int* __restrict__ col,
                       const int* __restrict__ hist, const int* __restrict__ boff,
                       uint* __restrict__ pairs, int E, int nbv, int nchunk) {
    extern __shared__ int lds[];          // gbase | cur
    int* gbase = lds;
    int* cur   = lds + nbv;
    int t = threadIdx.x, k = blockIdx.x;
    for (int i = t; i < nbv; i += 256) {
        gbase[i] = boff[i] + hist[(size_t)i * nchunk + k];
        cur[i] = 0;
    }
    __syncthreads();
    int start = k * CH, end = min(start + CH, E);
    for (int i = start + t; i < end; i += 256) {
        int c = col[i];
        int b = c >> 10;
        int rk = atomicAdd(&cur[b], 1);
        pairs[gbase[b] + rk] = ((uint)row[i] << 10) | (uint)(c & (BS - 1));
    }
}

// ---------- per-node count + in-bucket scan -> off, dinv ----------
__global__ __launch_bounds__(1024) void k_nscan(const uint* __restrict__ pairs,
                                                const int* __restrict__ boff,
                                                int* __restrict__ off, float* __restrict__ dinv,
                                                int N, int nbv, int E) {
    __shared__ int c[BS];
    __shared__ int s[BS];
    int b = blockIdx.x, t = threadIdx.x;
    c[t] = 0;
    __syncthreads();
    int st = boff[b], en = boff[b + 1];
    for (int i = st + t; i < en; i += 1024) atomicAdd(&c[pairs[i] & (BS - 1)], 1);
    __syncthreads();
    int v = c[t];
    s[t] = v;
    __syncthreads();
    for (int ofs = 1; ofs < 1024; ofs <<= 1) {
        int val = (t >= ofs) ? s[t - ofs] : 0;
        __syncthreads();
        if (t >= ofs) s[t] += val;
        __syncthreads();
    }
    int n = (b << 10) + t;
    if (n < N) {
        off[n] = st + s[t] - v;
        dinv[n] = rsqrtf((float)v + 1.0f);
    }
    if (b == nbv - 1 && t == 0) off[N] = E;
}

// ---------- place: per bucket, LDS cursors -> srow ----------
__global__ __launch_bounds__(1024) void k_place(const uint* __restrict__ pairs,
                                                const int* __restrict__ boff,
                                                const int* __restrict__ off,
                                                int* __restrict__ srow, int N) {
    __shared__ int so[BS];
    __shared__ int cu[BS];
    int b = blockIdx.x, t = threadIdx.x;
    int n = (b << 10) + t;
    so[t] = (n < N) ? off[n] : 0;
    cu[t] = 0;
    __syncthreads();
    int st = boff[b], en = boff[b + 1];
    for (int i = st + t; i < en; i += 1024) {
        uint v = pairs[i];
        int cl = v & (BS - 1);
        int p = so[cl] + atomicAdd(&cu[cl], 1);
        srow[p] = (int)(v >> 10);
    }
}

// ---------- W1 (f32 [128][16]) -> bf16 fragment table Wf[kk][lane][j] ----------
__global__ void k_wprep(const float* __restrict__ W1, short* __restrict__ Wf) {
    int t = threadIdx.x;
    for (int i = t; i < 4 * 64 * 8; i += 256) {
        int kk = i >> 9;
        int l  = (i >> 3) & 63;
        int j  = i & 7;
        int k  = kk * 32 + ((l >> 4) << 3) + j;
        int h  = l & 15;
        Wf[i] = f2bf(W1[k * HID + h]);
    }
}

// ---------- xw via MFMA: xws[n][h] = bf16(dinv[n] * (x @ W1)[n][h]) ----------
// One wave per 16 nodes; 4x mfma_f32_16x16x32_bf16 over K=128. No LDS.
__global__ void k_xwm(const float* __restrict__ x, const short* __restrict__ Wf,
                      const float* __restrict__ dinv, __hip_bfloat16* __restrict__ xws, int N) {
    int w = threadIdx.x >> 6, l = threadIdx.x & 63;
    int n0 = (blockIdx.x * 4 + w) * 16;
    if (n0 >= N) return;                 // N % 16 == 0: full waves only
    int rrow = n0 + (l & 15);
    int kbase = (l >> 4) << 3;           // 0,8,16,24
    const float* xr = x + (size_t)rrow * F_IN + kbase;
    f32x4 acc = {0.f, 0.f, 0.f, 0.f};
    #pragma unroll
    for (int kk = 0; kk < 4; ++kk) {
        const float4* p = reinterpret_cast<const float4*>(xr + kk * 32);
        float4 lo = p[0], hi = p[1];
        short8v a;
        a[0] = f2bf(lo.x); a[1] = f2bf(lo.y); a[2] = f2bf(lo.z); a[3] = f2bf(lo.w);
        a[4] = f2bf(hi.x); a[5] = f2bf(hi.y); a[6] = f2bf(hi.z); a[7] = f2bf(hi.w);
        short8v b = *reinterpret_cast<const short8v*>(Wf + (kk << 9) + (l << 3));
        acc = __builtin_amdgcn_mfma_f32_16x16x32_bf16(a, b, acc, 0, 0, 0);
    }
    int h = l & 15;
    #pragma unroll
    for (int j = 0; j < 4; ++j) {
        int n = n0 + ((l >> 4) << 2) + j;        // row = (lane>>4)*4 + reg  [m89]
        xws[(size_t)n * HID + h] = __float2bfloat16(acc[j] * dinv[n]);
    }
}

// ---------- layer-1 pull: hs = bf16(dinv * relu(dinv*sum + b1)) ----------
__global__ void k_agg1(const __hip_bfloat16* __restrict__ xws, const int* __restrict__ off,
                       const int* __restrict__ srow, const float* __restrict__ dinv,
                       const float* __restrict__ b1, __hip_bfloat16* __restrict__ hs, int N) {
    int n = (blockIdx.x * blockDim.x + threadIdx.x) >> 4;
    int l = threadIdx.x & 15;
    if (n >= N) return;
    int s = off[n], e = off[n + 1];
    float a0 = __bfloat162float(xws[(size_t)n * HID + l]);   // self loop
    float a1 = 0.f, a2 = 0.f, a3 = 0.f;
    int i = s;
    for (; i + 7 < e; i += 8) {
        int r0 = srow[i],     r1 = srow[i + 1], r2 = srow[i + 2], r3 = srow[i + 3];
        int r4 = srow[i + 4], r5 = srow[i + 5], r6 = srow[i + 6], r7 = srow[i + 7];
        a0 += __bfloat162float(xws[(size_t)r0 * HID + l]);
        a1 += __bfloat162float(xws[(size_t)r1 * HID + l]);
        a2 += __bfloat162float(xws[(size_t)r2 * HID + l]);
        a3 += __bfloat162float(xws[(size_t)r3 * HID + l]);
        a0 += __bfloat162float(xws[(size_t)r4 * HID + l]);
        a1 += __bfloat162float(xws[(size_t)r5 * HID + l]);
        a2 += __bfloat162float(xws[(size_t)r6 * HID + l]);
        a3 += __bfloat162float(xws[(size_t)r7 * HID + l]);
    }
    for (; i < e; ++i) a0 += __bfloat162float(xws[(size_t)srow[i] * HID + l]);
    float acc = (a0 + a1) + (a2 + a3);
    float d = dinv[n];
    float h = d * acc + b1[l];
    h = h > 0.f ? h : 0.f;
    hs[(size_t)n * HID + l] = __float2bfloat16(d * h);
}

// ---------- layer-2 pull + fused W2/b2/log_softmax ----------
__global__ void k_agg2(const __hip_bfloat16* __restrict__ hs, const int* __restrict__ off,
                       const int* __restrict__ srow, const float* __restrict__ dinv,
                       const float* __restrict__ W2, const float* __restrict__ b2,
                       float* __restrict__ out, int N) {
    __shared__ float gs[16][17];
    __shared__ float W2s[HID * NCLS];
    __shared__ float b2s[NCLS];
    int t = threadIdx.x;
    if (t < HID * NCLS) W2s[t] = W2[t];
    if (t < NCLS) b2s[t] = b2[t];
    int grp = t >> 4, l = t & 15;
    int n = blockIdx.x * 16 + grp;
    float g = 0.f;
    if (n < N) {
        int s = off[n], e = off[n + 1];
        float a0 = __bfloat162float(hs[(size_t)n * HID + l]);
        float a1 = 0.f, a2 = 0.f, a3 = 0.f;
        int i = s;
        for (; i + 7 < e; i += 8) {
            int r0 = srow[i],     r1 = srow[i + 1], r2 = srow[i + 2], r3 = srow[i + 3];
            int r4 = srow[i + 4], r5 = srow[i + 5], r6 = srow[i + 6], r7 = srow[i + 7];
            a0 += __bfloat162float(hs[(size_t)r0 * HID + l]);
            a1 += __bfloat162float(hs[(size_t)r1 * HID + l]);
            a2 += __bfloat162float(hs[(size_t)r2 * HID + l]);
            a3 += __bfloat162float(hs[(size_t)r3 * HID + l]);
            a0 += __bfloat162float(hs[(size_t)r4 * HID + l]);
            a1 += __bfloat162float(hs[(size_t)r5 * HID + l]);
            a2 += __bfloat162float(hs[(size_t)r6 * HID + l]);
            a3 += __bfloat162float(hs[(size_t)r7 * HID + l]);
        }
        for (; i < e; ++i) a0 += __bfloat162float(hs[(size_t)srow[i] * HID + l]);
        g = dinv[n] * ((a0 + a1) + (a2 + a3));
    }
    gs[grp][l] = g;
    __syncthreads();
    if (t < 16) {
        int n2 = blockIdx.x * 16 + t;
        if (n2 < N) {
            float v[NCLS];
            float m = -INFINITY;
            #pragma unroll
            for (int c = 0; c < NCLS; ++c) {
                float a = b2s[c];
                #pragma unroll
                for (int j = 0; j < HID; ++j) a += gs[t][j] * W2s[j * NCLS + c];
                v[c] = a;
                m = fmaxf(m, a);
            }
            float ssum = 0.f;
            #pragma unroll
            for (int c = 0; c < NCLS; ++c) ssum += __expf(v[c] - m);
            float lse = m + __logf(ssum);
            #pragma unroll
            for (int c = 0; c < NCLS; ++c) out[(size_t)n2 * NCLS + c] = v[c] - lse;
        }
    }
}

extern "C" void kernel_launch(void* const* d_in, const int* in_sizes, int n_in,
                              void* d_out, int out_size, void* d_ws, size_t ws_size,
                              hipStream_t stream) {
    const float* x  = (const float*)d_in[0];
    const int*   ei = (const int*)d_in[1];
    const float* W1 = (const float*)d_in[2];
    const float* b1 = (const float*)d_in[3];
    const float* W2 = (const float*)d_in[4];
    const float* b2 = (const float*)d_in[5];
    float* out = (float*)d_out;

    const int N = in_sizes[0] / F_IN;        // 100000
    const int E = in_sizes[1] / 2;           // 3200000
    const int* row = ei;                     // source
    const int* col = ei + E;                 // target

    const int nbv = (N + BS - 1) / BS;       // 98 buckets (<=128 for k_bscan)
    const int nchunk = (E + CH - 1) / CH;    // 391 chunks (<= 64*KPL)

    char* ws = (char*)d_ws;
    auto alignup = [](size_t v) { return (v + 255) & ~(size_t)255; };
    size_t offb = 0;
    int*   hist = (int*)  (ws + offb); offb += alignup((size_t)nbv * nchunk * 4); // ~153 KB
    int*   bcnt = (int*)  (ws + offb); offb += alignup((size_t)(nbv + 1) * 4);
    int*   boff = (int*)  (ws + offb); offb += alignup((size_t)(nbv + 1) * 4);
    int*   off  = (int*)  (ws + offb); offb += alignup((size_t)(N + 1) * 4);
    float* dinv = (float*)(ws + offb); offb += alignup((size_t)N * 4);
    short* Wf   = (short*)(ws + offb); offb += alignup((size_t)4 * 64 * 8 * 2);
    uint*  pairs= (uint*) (ws + offb); offb += alignup((size_t)E * 4);
    int*   srow = (int*)  (ws + offb); offb += alignup((size_t)E * 4);
    __hip_bfloat16* xws = (__hip_bfloat16*)(ws + offb); offb += alignup((size_t)N * HID * 2);
    __hip_bfloat16* hs  = (__hip_bfloat16*)(ws + offb); offb += alignup((size_t)N * HID * 2);
    (void)ws_size; (void)n_in; (void)out_size;

    size_t histB = (size_t)nbv * 4;
    const int nxb = ((N / 16) + 3) / 4;      // k_xwm blocks (4 waves each)

    k_hist2<<<nchunk, 256, histB,      stream>>>(col, hist, E, nbv, nchunk);
    k_cscan<<<(nbv + 3) / 4, 256, 0,   stream>>>(hist, bcnt, nchunk, nbv);
    k_bscan<<<1, 128, 0,               stream>>>(bcnt, boff, nbv, E);
    k_binW <<<nchunk, 256, 2 * histB,  stream>>>(row, col, hist, boff, pairs, E, nbv, nchunk);
    k_nscan<<<nbv, 1024, 0,            stream>>>(pairs, boff, off, dinv, N, nbv, E);
    k_wprep<<<1, 256, 0,               stream>>>(W1, Wf);
    k_xwm  <<<nxb, 256, 0,             stream>>>(x, Wf, dinv, xws, N);
    k_place<<<nbv, 1024, 0,            stream>>>(pairs, boff, off, srow, N);
    k_agg1 <<<(N * HID + 255) / 256, 256, 0, stream>>>(xws, off, srow, dinv, b1, hs, N);
    k_agg2 <<<(N + 15) / 16, 256, 0,   stream>>>(hs, off, srow, dinv, W2, b2, out, N);
}

// Round 10
// 145.073 us; speedup vs baseline: 1.5551x; 1.1549x over previous
//
#include <hip/hip_runtime.h>
#include <hip/hip_bf16.h>
#include <math.h>

#define F_IN 128
#define HID  16
#define NCLS 10
#define BS   1024                // nodes per bucket (pow2)
#define CH   8192                // edges per binning chunk
#define KPL  8                   // chunks per lane in column scan (<=512 chunks)

typedef unsigned int uint;
typedef unsigned short ushort;
typedef __attribute__((ext_vector_type(8))) short short8v;
typedef __attribute__((ext_vector_type(4))) float f32x4;

static __device__ __forceinline__ short f2bf(float f) {
    __hip_bfloat16 h = __float2bfloat16(f);
    return *reinterpret_cast<short*>(&h);
}
static __device__ __forceinline__ float bflo(uint u) {   // low bf16 -> f32
    union { uint x; float f; } c; c.x = u << 16; return c.f;
}
static __device__ __forceinline__ float bfhi(uint u) {   // high bf16 -> f32
    union { uint x; float f; } c; c.x = u & 0xffff0000u; return c.f;
}
static __device__ __forceinline__ uint packbf(float f0, float f1) {
    return (uint)(ushort)f2bf(f0) | ((uint)(ushort)f2bf(f1) << 16);
}

// ---------- chunk x bucket histogram, bucket-major: hist[b * nchunk + k] ----------
__global__ void k_hist2(const int* __restrict__ col, int* __restrict__ hist,
                        int E, int nbv, int nchunk) {
    extern __shared__ int h[];
    int t = threadIdx.x, k = blockIdx.x;
    for (int i = t; i < nbv; i += 512) h[i] = 0;
    __syncthreads();
    int start = k * CH, end = min(start + CH, E);
    for (int i = start + t; i < end; i += 512) atomicAdd(&h[col[i] >> 10], 1);
    __syncthreads();
    for (int i = t; i < nbv; i += 512) hist[(size_t)i * nchunk + k] = h[i];
}

// ---------- column scan: one wave per bucket, contiguous reads ----------
__global__ void k_cscan(int* __restrict__ hist, int* __restrict__ bcnt, int nchunk, int nbv) {
    int wave = threadIdx.x >> 6, lane = threadIdx.x & 63;
    int b = blockIdx.x * 4 + wave;
    if (b >= nbv) return;
    int* hb = hist + (size_t)b * nchunk;
    int vals[KPL];
    int ls = 0;
    #pragma unroll
    for (int i = 0; i < KPL; ++i) {
        int k = lane * KPL + i;
        vals[i] = (k < nchunk) ? hb[k] : 0;
        ls += vals[i];
    }
    int inc = ls;
    #pragma unroll
    for (int d = 1; d < 64; d <<= 1) {
        int v = __shfl_up(inc, d, 64);
        if (lane >= d) inc += v;
    }
    int run = inc - ls;
    #pragma unroll
    for (int i = 0; i < KPL; ++i) {
        int k = lane * KPL + i;
        if (k < nchunk) { hb[k] = run; run += vals[i]; }
    }
    if (lane == 63) bcnt[b] = inc;
}

// ---------- scan bucket totals -> boff ----------
__global__ void k_bscan(const int* __restrict__ bcnt, int* __restrict__ boff, int nbv, int E) {
    __shared__ int s[128];
    int t = threadIdx.x;
    int v = (t < nbv) ? bcnt[t] : 0;
    s[t] = v;
    __syncthreads();
    for (int ofs = 1; ofs < 128; ofs <<= 1) {
        int val = (t >= ofs) ? s[t - ofs] : 0;
        __syncthreads();
        if (t >= ofs) s[t] += val;
        __syncthreads();
    }
    if (t < nbv) boff[t] = s[t] - v;
    if (t == nbv) boff[t] = E;
}

// ---------- bin: place edges via precomputed bases + LDS cursors ----------
__global__ void k_binW(const int* __restrict__ row, const int* __restrict__ col,
                       const int* __restrict__ hist, const int* __restrict__ boff,
                       uint* __restrict__ pairs, int E, int nbv, int nchunk) {
    extern __shared__ int lds[];          // gbase | cur
    int* gbase = lds;
    int* cur   = lds + nbv;
    int t = threadIdx.x, k = blockIdx.x;
    for (int i = t; i < nbv; i += 512) {
        gbase[i] = boff[i] + hist[(size_t)i * nchunk + k];
        cur[i] = 0;
    }
    __syncthreads();
    int start = k * CH, end = min(start + CH, E);
    for (int i = start + t; i < end; i += 512) {
        int c = col[i];
        int b = c >> 10;
        int rk = atomicAdd(&cur[b], 1);
        pairs[gbase[b] + rk] = ((uint)row[i] << 10) | (uint)(c & (BS - 1));
    }
}

// ---------- fused: per-node count + scan -> off,dinv; then place -> srow ----------
__global__ __launch_bounds__(1024) void k_nsp(const uint* __restrict__ pairs,
                                              const int* __restrict__ boff,
                                              int* __restrict__ off, float* __restrict__ dinv,
                                              int* __restrict__ srow, int N, int nbv, int E) {
    __shared__ int c[BS];
    __shared__ int s[BS];
    int b = blockIdx.x, t = threadIdx.x;
    c[t] = 0;
    __syncthreads();
    int st = boff[b], en = boff[b + 1];
    for (int i = st + t; i < en; i += 1024) atomicAdd(&c[pairs[i] & (BS - 1)], 1);
    __syncthreads();
    int v = c[t];
    s[t] = v;
    __syncthreads();
    for (int ofs = 1; ofs < 1024; ofs <<= 1) {
        int val = (t >= ofs) ? s[t - ofs] : 0;
        __syncthreads();
        if (t >= ofs) s[t] += val;
        __syncthreads();
    }
    int mybase = st + s[t] - v;
    int n = (b << 10) + t;
    if (n < N) {
        off[n] = mybase;
        dinv[n] = rsqrtf((float)v + 1.0f);
    }
    if (b == nbv - 1 && t == 0) off[N] = E;
    __syncthreads();
    c[t] = mybase;                        // reuse c as node base
    s[t] = 0;                             // reuse s as cursor
    __syncthreads();
    for (int i = st + t; i < en; i += 1024) {
        uint pv = pairs[i];
        int cl = pv & (BS - 1);
        int p = c[cl] + atomicAdd(&s[cl], 1);
        srow[p] = (int)(pv >> 10);
    }
}

// ---------- xw via MFMA (W1 fragment built inline): xws = bf16(dinv * x@W1) ----------
__global__ void k_xwm(const float* __restrict__ x, const float* __restrict__ W1,
                      const float* __restrict__ dinv, __hip_bfloat16* __restrict__ xws, int N) {
    int w = threadIdx.x >> 6, l = threadIdx.x & 63;
    int n0 = (blockIdx.x * 4 + w) * 16;
    if (n0 >= N) return;                 // N % 16 == 0: full waves only
    int h = l & 15;
    int kb8 = (l >> 4) << 3;             // 0,8,16,24
    short8v bfrag[4];
    #pragma unroll
    for (int kk = 0; kk < 4; ++kk) {
        #pragma unroll
        for (int j = 0; j < 8; ++j) {
            int k = kk * 32 + kb8 + j;
            bfrag[kk][j] = f2bf(W1[k * HID + h]);
        }
    }
    int rrow = n0 + h;
    const float* xr = x + (size_t)rrow * F_IN + kb8;
    f32x4 acc = {0.f, 0.f, 0.f, 0.f};
    #pragma unroll
    for (int kk = 0; kk < 4; ++kk) {
        const float4* p = reinterpret_cast<const float4*>(xr + kk * 32);
        float4 lo = p[0], hi = p[1];
        short8v a;
        a[0] = f2bf(lo.x); a[1] = f2bf(lo.y); a[2] = f2bf(lo.z); a[3] = f2bf(lo.w);
        a[4] = f2bf(hi.x); a[5] = f2bf(hi.y); a[6] = f2bf(hi.z); a[7] = f2bf(hi.w);
        acc = __builtin_amdgcn_mfma_f32_16x16x32_bf16(a, bfrag[kk], acc, 0, 0, 0);
    }
    #pragma unroll
    for (int j = 0; j < 4; ++j) {
        int n = n0 + ((l >> 4) << 2) + j;        // row = (lane>>4)*4 + reg  [m89]
        xws[(size_t)n * HID + h] = __float2bfloat16(acc[j] * dinv[n]);
    }
}

// ---------- layer-1 pull (8 lanes/node, uint = 2 bf16 per load) ----------
__global__ void k_agg1(const uint* __restrict__ xws32, const int* __restrict__ off,
                       const int* __restrict__ srow, const float* __restrict__ dinv,
                       const float* __restrict__ b1, uint* __restrict__ hs32, int N) {
    int gid = blockIdx.x * blockDim.x + threadIdx.x;
    int n = gid >> 3;
    int p = threadIdx.x & 7;
    if (n >= N) return;
    int s = off[n], e = off[n + 1];
    uint v = xws32[(size_t)n * 8 + p];            // self loop
    float a0 = bflo(v), b0 = bfhi(v);
    float a1 = 0.f, b1a = 0.f, a2 = 0.f, b2a = 0.f, a3 = 0.f, b3a = 0.f;
    int i = s;
    for (; i + 7 < e; i += 8) {
        int r0 = srow[i],     r1 = srow[i + 1], r2 = srow[i + 2], r3 = srow[i + 3];
        int r4 = srow[i + 4], r5 = srow[i + 5], r6 = srow[i + 6], r7 = srow[i + 7];
        uint v0 = xws32[(size_t)r0 * 8 + p], v1 = xws32[(size_t)r1 * 8 + p];
        uint v2 = xws32[(size_t)r2 * 8 + p], v3 = xws32[(size_t)r3 * 8 + p];
        uint v4 = xws32[(size_t)r4 * 8 + p], v5 = xws32[(size_t)r5 * 8 + p];
        uint v6 = xws32[(size_t)r6 * 8 + p], v7 = xws32[(size_t)r7 * 8 + p];
        a0 += bflo(v0); b0 += bfhi(v0);  a1 += bflo(v1); b1a += bfhi(v1);
        a2 += bflo(v2); b2a += bfhi(v2); a3 += bflo(v3); b3a += bfhi(v3);
        a0 += bflo(v4); b0 += bfhi(v4);  a1 += bflo(v5); b1a += bfhi(v5);
        a2 += bflo(v6); b2a += bfhi(v6); a3 += bflo(v7); b3a += bfhi(v7);
    }
    for (; i < e; ++i) {
        uint vv = xws32[(size_t)srow[i] * 8 + p];
        a0 += bflo(vv); b0 += bfhi(vv);
    }
    float sl = (a0 + a1) + (a2 + a3);
    float sh = (b0 + b1a) + (b2a + b3a);
    float d = dinv[n];
    float h0 = d * sl + b1[2 * p];
    float h1 = d * sh + b1[2 * p + 1];
    h0 = h0 > 0.f ? h0 : 0.f;
    h1 = h1 > 0.f ? h1 : 0.f;
    hs32[(size_t)n * 8 + p] = packbf(d * h0, d * h1);
}

// ---------- layer-2 pull (8 lanes/node) + fused W2/b2/log_softmax ----------
__global__ void k_agg2(const uint* __restrict__ hs32, const int* __restrict__ off,
                       const int* __restrict__ srow, const float* __restrict__ dinv,
                       const float* __restrict__ W2, const float* __restrict__ b2,
                       float* __restrict__ out, int N) {
    __shared__ float gs[32][17];
    __shared__ float W2s[HID * NCLS];
    __shared__ float b2s[NCLS];
    int t = threadIdx.x;
    if (t < HID * NCLS) W2s[t] = W2[t];
    if (t < NCLS) b2s[t] = b2[t];
    int grp = t >> 3, p = t & 7;
    int n = blockIdx.x * 32 + grp;
    float g0 = 0.f, g1 = 0.f;
    if (n < N) {
        int s = off[n], e = off[n + 1];
        uint v = hs32[(size_t)n * 8 + p];
        float a0 = bflo(v), b0 = bfhi(v);
        float a1 = 0.f, b1a = 0.f, a2 = 0.f, b2a = 0.f, a3 = 0.f, b3a = 0.f;
        int i = s;
        for (; i + 7 < e; i += 8) {
            int r0 = srow[i],     r1 = srow[i + 1], r2 = srow[i + 2], r3 = srow[i + 3];
            int r4 = srow[i + 4], r5 = srow[i + 5], r6 = srow[i + 6], r7 = srow[i + 7];
            uint v0 = hs32[(size_t)r0 * 8 + p], v1 = hs32[(size_t)r1 * 8 + p];
            uint v2 = hs32[(size_t)r2 * 8 + p], v3 = hs32[(size_t)r3 * 8 + p];
            uint v4 = hs32[(size_t)r4 * 8 + p], v5 = hs32[(size_t)r5 * 8 + p];
            uint v6 = hs32[(size_t)r6 * 8 + p], v7 = hs32[(size_t)r7 * 8 + p];
            a0 += bflo(v0); b0 += bfhi(v0);  a1 += bflo(v1); b1a += bfhi(v1);
            a2 += bflo(v2); b2a += bfhi(v2); a3 += bflo(v3); b3a += bfhi(v3);
            a0 += bflo(v4); b0 += bfhi(v4);  a1 += bflo(v5); b1a += bfhi(v5);
            a2 += bflo(v6); b2a += bfhi(v6); a3 += bflo(v7); b3a += bfhi(v7);
        }
        for (; i < e; ++i) {
            uint vv = hs32[(size_t)srow[i] * 8 + p];
            a0 += bflo(vv); b0 += bfhi(vv);
        }
        float d = dinv[n];
        g0 = d * ((a0 + a1) + (a2 + a3));
        g1 = d * ((b0 + b1a) + (b2a + b3a));
    }
    gs[grp][2 * p]     = g0;
    gs[grp][2 * p + 1] = g1;
    __syncthreads();
    if (t < 32) {
        int n2 = blockIdx.x * 32 + t;
        if (n2 < N) {
            float v[NCLS];
            float m = -INFINITY;
            #pragma unroll
            for (int c = 0; c < NCLS; ++c) {
                float a = b2s[c];
                #pragma unroll
                for (int j = 0; j < HID; ++j) a += gs[t][j] * W2s[j * NCLS + c];
                v[c] = a;
                m = fmaxf(m, a);
            }
            float ssum = 0.f;
            #pragma unroll
            for (int c = 0; c < NCLS; ++c) ssum += __expf(v[c] - m);
            float lse = m + __logf(ssum);
            #pragma unroll
            for (int c = 0; c < NCLS; ++c) out[(size_t)n2 * NCLS + c] = v[c] - lse;
        }
    }
}

extern "C" void kernel_launch(void* const* d_in, const int* in_sizes, int n_in,
                              void* d_out, int out_size, void* d_ws, size_t ws_size,
                              hipStream_t stream) {
    const float* x  = (const float*)d_in[0];
    const int*   ei = (const int*)d_in[1];
    const float* W1 = (const float*)d_in[2];
    const float* b1 = (const float*)d_in[3];
    const float* W2 = (const float*)d_in[4];
    const float* b2 = (const float*)d_in[5];
    float* out = (float*)d_out;

    const int N = in_sizes[0] / F_IN;        // 100000
    const int E = in_sizes[1] / 2;           // 3200000
    const int* row = ei;                     // source
    const int* col = ei + E;                 // target

    const int nbv = (N + BS - 1) / BS;       // 98 buckets (<=128 for k_bscan)
    const int nchunk = (E + CH - 1) / CH;    // 391 chunks (<= 64*KPL)

    char* ws = (char*)d_ws;
    auto alignup = [](size_t v) { return (v + 255) & ~(size_t)255; };
    size_t offb = 0;
    int*   hist = (int*)  (ws + offb); offb += alignup((size_t)nbv * nchunk * 4);
    int*   bcnt = (int*)  (ws + offb); offb += alignup((size_t)(nbv + 1) * 4);
    int*   boff = (int*)  (ws + offb); offb += alignup((size_t)(nbv + 1) * 4);
    int*   off  = (int*)  (ws + offb); offb += alignup((size_t)(N + 1) * 4);
    float* dinv = (float*)(ws + offb); offb += alignup((size_t)N * 4);
    uint*  pairs= (uint*) (ws + offb); offb += alignup((size_t)E * 4);
    int*   srow = (int*)  (ws + offb); offb += alignup((size_t)E * 4);
    uint*  xws  = (uint*) (ws + offb); offb += alignup((size_t)N * HID * 2);
    uint*  hs   = (uint*) (ws + offb); offb += alignup((size_t)N * HID * 2);
    (void)ws_size; (void)n_in; (void)out_size;

    size_t histB = (size_t)nbv * 4;
    const int nxb = ((N / 16) + 3) / 4;      // k_xwm blocks (4 waves each)

    k_hist2<<<nchunk, 512, histB,      stream>>>(col, hist, E, nbv, nchunk);
    k_cscan<<<(nbv + 3) / 4, 256, 0,   stream>>>(hist, bcnt, nchunk, nbv);
    k_bscan<<<1, 128, 0,               stream>>>(bcnt, boff, nbv, E);
    k_binW <<<nchunk, 512, 2 * histB,  stream>>>(row, col, hist, boff, pairs, E, nbv, nchunk);
    k_nsp  <<<nbv, 1024, 0,            stream>>>(pairs, boff, off, dinv, srow, N, nbv, E);
    k_xwm  <<<nxb, 256, 0,             stream>>>(x, W1, dinv, (__hip_bfloat16*)xws, N);
    k_agg1 <<<(N * 8 + 255) / 256, 256, 0, stream>>>(xws, off, srow, dinv, b1, hs, N);
    k_agg2 <<<(N * 8 + 255) / 256, 256, 0, stream>>>(hs, off, srow, dinv, W2, b2, out, N);
}

// Round 11
// 123.693 us; speedup vs baseline: 1.8238x; 1.1728x over previous
//
#include <hip/hip_runtime.h>
#include <hip/hip_bf16.h>
#include <math.h>

#define F_IN 128
#define HID  16
#define NCLS 10
#define BS   256                 // nodes per bucket (pow2)
#define CH   16384               // edges per binning chunk
#define KPL  4                   // chunks per lane in column scan (<=256 chunks)

typedef unsigned int uint;
typedef unsigned short ushort;
typedef __attribute__((ext_vector_type(8))) short short8v;
typedef __attribute__((ext_vector_type(4))) float f32x4;

static __device__ __forceinline__ short f2bf(float f) {
    __hip_bfloat16 h = __float2bfloat16(f);
    return *reinterpret_cast<short*>(&h);
}
static __device__ __forceinline__ float bflo(uint u) {   // low bf16 -> f32
    union { uint x; float f; } c; c.x = u << 16; return c.f;
}
static __device__ __forceinline__ float bfhi(uint u) {   // high bf16 -> f32
    union { uint x; float f; } c; c.x = u & 0xffff0000u; return c.f;
}
static __device__ __forceinline__ uint packbf(float f0, float f1) {
    return (uint)(ushort)f2bf(f0) | ((uint)(ushort)f2bf(f1) << 16);
}

// ---------- chunk x bucket histogram, bucket-major: hist[b * nchunk + k] ----------
__global__ __launch_bounds__(1024) void k_hist2(const int* __restrict__ col, int* __restrict__ hist,
                                                int E, int nbv, int nchunk) {
    extern __shared__ int h[];
    int t = threadIdx.x, k = blockIdx.x;
    for (int i = t; i < nbv; i += 1024) h[i] = 0;
    __syncthreads();
    int start = k * CH, end = min(start + CH, E);
    for (int i = start + t; i < end; i += 1024) atomicAdd(&h[col[i] >> 8], 1);
    __syncthreads();
    for (int i = t; i < nbv; i += 1024) hist[(size_t)i * nchunk + k] = h[i];
}

// ---------- column scan: one wave per bucket, contiguous reads ----------
__global__ void k_cscan(int* __restrict__ hist, int* __restrict__ bcnt, int nchunk, int nbv) {
    int wave = threadIdx.x >> 6, lane = threadIdx.x & 63;
    int b = blockIdx.x * 4 + wave;
    if (b >= nbv) return;
    int* hb = hist + (size_t)b * nchunk;
    int vals[KPL];
    int ls = 0;
    #pragma unroll
    for (int i = 0; i < KPL; ++i) {
        int k = lane * KPL + i;
        vals[i] = (k < nchunk) ? hb[k] : 0;
        ls += vals[i];
    }
    int inc = ls;
    #pragma unroll
    for (int d = 1; d < 64; d <<= 1) {
        int v = __shfl_up(inc, d, 64);
        if (lane >= d) inc += v;
    }
    int run = inc - ls;
    #pragma unroll
    for (int i = 0; i < KPL; ++i) {
        int k = lane * KPL + i;
        if (k < nchunk) { hb[k] = run; run += vals[i]; }
    }
    if (lane == 63) bcnt[b] = inc;
}

// ---------- scan bucket totals -> boff (nbv <= 511) ----------
__global__ void k_bscan(const int* __restrict__ bcnt, int* __restrict__ boff, int nbv, int E) {
    __shared__ int s[512];
    int t = threadIdx.x;
    int v = (t < nbv) ? bcnt[t] : 0;
    s[t] = v;
    __syncthreads();
    for (int ofs = 1; ofs < 512; ofs <<= 1) {
        int val = (t >= ofs) ? s[t - ofs] : 0;
        __syncthreads();
        if (t >= ofs) s[t] += val;
        __syncthreads();
    }
    if (t < nbv) boff[t] = s[t] - v;
    if (t == nbv) boff[t] = E;
}

// ---------- bin: place edges via precomputed bases + LDS cursors ----------
__global__ __launch_bounds__(1024) void k_binW(const int* __restrict__ row, const int* __restrict__ col,
                                               const int* __restrict__ hist, const int* __restrict__ boff,
                                               uint* __restrict__ pairs, int E, int nbv, int nchunk) {
    extern __shared__ int lds[];          // gbase | cur
    int* gbase = lds;
    int* cur   = lds + nbv;
    int t = threadIdx.x, k = blockIdx.x;
    for (int i = t; i < nbv; i += 1024) {
        gbase[i] = boff[i] + hist[(size_t)i * nchunk + k];
        cur[i] = 0;
    }
    __syncthreads();
    int start = k * CH, end = min(start + CH, E);
    for (int i = start + t; i < end; i += 1024) {
        int c = col[i];
        int b = c >> 8;
        int rk = atomicAdd(&cur[b], 1);
        pairs[gbase[b] + rk] = ((uint)row[i] << 8) | (uint)(c & (BS - 1));
    }
}

// ---------- fused: per-node count + scan -> off,dinv; then place -> srow ----------
__global__ __launch_bounds__(1024) void k_nsp(const uint* __restrict__ pairs,
                                              const int* __restrict__ boff,
                                              int* __restrict__ off, float* __restrict__ dinv,
                                              int* __restrict__ srow, int N, int nbv, int E) {
    __shared__ int c[BS];
    __shared__ int s[BS];
    int b = blockIdx.x, t = threadIdx.x;
    if (t < BS) c[t] = 0;
    __syncthreads();
    int st = boff[b], en = boff[b + 1];
    for (int i = st + t; i < en; i += 1024) atomicAdd(&c[pairs[i] & (BS - 1)], 1);
    __syncthreads();
    int v = 0;
    if (t < BS) { v = c[t]; s[t] = v; }
    __syncthreads();
    for (int ofs = 1; ofs < BS; ofs <<= 1) {
        int val = 0;
        if (t < BS && t >= ofs) val = s[t - ofs];
        __syncthreads();
        if (t < BS && t >= ofs) s[t] += val;
        __syncthreads();
    }
    int mybase = 0;
    if (t < BS) {
        mybase = st + s[t] - v;
        int n = (b << 8) + t;
        if (n < N) {
            off[n] = mybase;
            dinv[n] = rsqrtf((float)v + 1.0f);
        }
    }
    if (b == nbv - 1 && t == 0) off[N] = E;
    __syncthreads();
    if (t < BS) { c[t] = mybase; s[t] = 0; }   // reuse: c = node base, s = cursor
    __syncthreads();
    for (int i = st + t; i < en; i += 1024) {
        uint pv = pairs[i];
        int cl = pv & (BS - 1);
        int p = c[cl] + atomicAdd(&s[cl], 1);
        srow[p] = (int)(pv >> 8);
    }
}

// ---------- xw via MFMA (W1 fragment built inline): xws = bf16(dinv * x@W1) ----------
__global__ void k_xwm(const float* __restrict__ x, const float* __restrict__ W1,
                      const float* __restrict__ dinv, __hip_bfloat16* __restrict__ xws, int N) {
    int w = threadIdx.x >> 6, l = threadIdx.x & 63;
    int n0 = (blockIdx.x * 4 + w) * 16;
    if (n0 >= N) return;                 // N % 16 == 0: full waves only
    int h = l & 15;
    int kb8 = (l >> 4) << 3;             // 0,8,16,24
    short8v bfrag[4];
    #pragma unroll
    for (int kk = 0; kk < 4; ++kk) {
        #pragma unroll
        for (int j = 0; j < 8; ++j) {
            int k = kk * 32 + kb8 + j;
            bfrag[kk][j] = f2bf(W1[k * HID + h]);
        }
    }
    int rrow = n0 + h;
    const float* xr = x + (size_t)rrow * F_IN + kb8;
    f32x4 acc = {0.f, 0.f, 0.f, 0.f};
    #pragma unroll
    for (int kk = 0; kk < 4; ++kk) {
        const float4* p = reinterpret_cast<const float4*>(xr + kk * 32);
        float4 lo = p[0], hi = p[1];
        short8v a;
        a[0] = f2bf(lo.x); a[1] = f2bf(lo.y); a[2] = f2bf(lo.z); a[3] = f2bf(lo.w);
        a[4] = f2bf(hi.x); a[5] = f2bf(hi.y); a[6] = f2bf(hi.z); a[7] = f2bf(hi.w);
        acc = __builtin_amdgcn_mfma_f32_16x16x32_bf16(a, bfrag[kk], acc, 0, 0, 0);
    }
    #pragma unroll
    for (int j = 0; j < 4; ++j) {
        int n = n0 + ((l >> 4) << 2) + j;        // row = (lane>>4)*4 + reg  [m89]
        xws[(size_t)n * HID + h] = __float2bfloat16(acc[j] * dinv[n]);
    }
}

// ---------- layer-1 pull (8 lanes/node, uint = 2 bf16 per load) ----------
__global__ void k_agg1(const uint* __restrict__ xws32, const int* __restrict__ off,
                       const int* __restrict__ srow, const float* __restrict__ dinv,
                       const float* __restrict__ b1, uint* __restrict__ hs32, int N) {
    int gid = blockIdx.x * blockDim.x + threadIdx.x;
    int n = gid >> 3;
    int p = threadIdx.x & 7;
    if (n >= N) return;
    int s = off[n], e = off[n + 1];
    uint v = xws32[(size_t)n * 8 + p];            // self loop
    float a0 = bflo(v), b0 = bfhi(v);
    float a1 = 0.f, b1a = 0.f, a2 = 0.f, b2a = 0.f, a3 = 0.f, b3a = 0.f;
    int i = s;
    for (; i + 7 < e; i += 8) {
        int r0 = srow[i],     r1 = srow[i + 1], r2 = srow[i + 2], r3 = srow[i + 3];
        int r4 = srow[i + 4], r5 = srow[i + 5], r6 = srow[i + 6], r7 = srow[i + 7];
        uint v0 = xws32[(size_t)r0 * 8 + p], v1 = xws32[(size_t)r1 * 8 + p];
        uint v2 = xws32[(size_t)r2 * 8 + p], v3 = xws32[(size_t)r3 * 8 + p];
        uint v4 = xws32[(size_t)r4 * 8 + p], v5 = xws32[(size_t)r5 * 8 + p];
        uint v6 = xws32[(size_t)r6 * 8 + p], v7 = xws32[(size_t)r7 * 8 + p];
        a0 += bflo(v0); b0 += bfhi(v0);  a1 += bflo(v1); b1a += bfhi(v1);
        a2 += bflo(v2); b2a += bfhi(v2); a3 += bflo(v3); b3a += bfhi(v3);
        a0 += bflo(v4); b0 += bfhi(v4);  a1 += bflo(v5); b1a += bfhi(v5);
        a2 += bflo(v6); b2a += bfhi(v6); a3 += bflo(v7); b3a += bfhi(v7);
    }
    for (; i < e; ++i) {
        uint vv = xws32[(size_t)srow[i] * 8 + p];
        a0 += bflo(vv); b0 += bfhi(vv);
    }
    float sl = (a0 + a1) + (a2 + a3);
    float sh = (b0 + b1a) + (b2a + b3a);
    float d = dinv[n];
    float h0 = d * sl + b1[2 * p];
    float h1 = d * sh + b1[2 * p + 1];
    h0 = h0 > 0.f ? h0 : 0.f;
    h1 = h1 > 0.f ? h1 : 0.f;
    hs32[(size_t)n * 8 + p] = packbf(d * h0, d * h1);
}

// ---------- layer-2 pull (8 lanes/node) + fused W2/b2/log_softmax ----------
__global__ void k_agg2(const uint* __restrict__ hs32, const int* __restrict__ off,
                       const int* __restrict__ srow, const float* __restrict__ dinv,
                       const float* __restrict__ W2, const float* __restrict__ b2,
                       float* __restrict__ out, int N) {
    __shared__ float gs[32][17];
    __shared__ float W2s[HID * NCLS];
    __shared__ float b2s[NCLS];
    int t = threadIdx.x;
    if (t < HID * NCLS) W2s[t] = W2[t];
    if (t < NCLS) b2s[t] = b2[t];
    int grp = t >> 3, p = t & 7;
    int n = blockIdx.x * 32 + grp;
    float g0 = 0.f, g1 = 0.f;
    if (n < N) {
        int s = off[n], e = off[n + 1];
        uint v = hs32[(size_t)n * 8 + p];
        float a0 = bflo(v), b0 = bfhi(v);
        float a1 = 0.f, b1a = 0.f, a2 = 0.f, b2a = 0.f, a3 = 0.f, b3a = 0.f;
        int i = s;
        for (; i + 7 < e; i += 8) {
            int r0 = srow[i],     r1 = srow[i + 1], r2 = srow[i + 2], r3 = srow[i + 3];
            int r4 = srow[i + 4], r5 = srow[i + 5], r6 = srow[i + 6], r7 = srow[i + 7];
            uint v0 = hs32[(size_t)r0 * 8 + p], v1 = hs32[(size_t)r1 * 8 + p];
            uint v2 = hs32[(size_t)r2 * 8 + p], v3 = hs32[(size_t)r3 * 8 + p];
            uint v4 = hs32[(size_t)r4 * 8 + p], v5 = hs32[(size_t)r5 * 8 + p];
            uint v6 = hs32[(size_t)r6 * 8 + p], v7 = hs32[(size_t)r7 * 8 + p];
            a0 += bflo(v0); b0 += bfhi(v0);  a1 += bflo(v1); b1a += bfhi(v1);
            a2 += bflo(v2); b2a += bfhi(v2); a3 += bflo(v3); b3a += bfhi(v3);
            a0 += bflo(v4); b0 += bfhi(v4);  a1 += bflo(v5); b1a += bfhi(v5);
            a2 += bflo(v6); b2a += bfhi(v6); a3 += bflo(v7); b3a += bfhi(v7);
        }
        for (; i < e; ++i) {
            uint vv = hs32[(size_t)srow[i] * 8 + p];
            a0 += bflo(vv); b0 += bfhi(vv);
        }
        float d = dinv[n];
        g0 = d * ((a0 + a1) + (a2 + a3));
        g1 = d * ((b0 + b1a) + (b2a + b3a));
    }
    gs[grp][2 * p]     = g0;
    gs[grp][2 * p + 1] = g1;
    __syncthreads();
    if (t < 32) {
        int n2 = blockIdx.x * 32 + t;
        if (n2 < N) {
            float v[NCLS];
            float m = -INFINITY;
            #pragma unroll
            for (int c = 0; c < NCLS; ++c) {
                float a = b2s[c];
                #pragma unroll
                for (int j = 0; j < HID; ++j) a += gs[t][j] * W2s[j * NCLS + c];
                v[c] = a;
                m = fmaxf(m, a);
            }
            float ssum = 0.f;
            #pragma unroll
            for (int c = 0; c < NCLS; ++c) ssum += __expf(v[c] - m);
            float lse = m + __logf(ssum);
            #pragma unroll
            for (int c = 0; c < NCLS; ++c) out[(size_t)n2 * NCLS + c] = v[c] - lse;
        }
    }
}

extern "C" void kernel_launch(void* const* d_in, const int* in_sizes, int n_in,
                              void* d_out, int out_size, void* d_ws, size_t ws_size,
                              hipStream_t stream) {
    const float* x  = (const float*)d_in[0];
    const int*   ei = (const int*)d_in[1];
    const float* W1 = (const float*)d_in[2];
    const float* b1 = (const float*)d_in[3];
    const float* W2 = (const float*)d_in[4];
    const float* b2 = (const float*)d_in[5];
    float* out = (float*)d_out;

    const int N = in_sizes[0] / F_IN;        // 100000
    const int E = in_sizes[1] / 2;           // 3200000
    const int* row = ei;                     // source
    const int* col = ei + E;                 // target

    const int nbv = (N + BS - 1) / BS;       // 391 buckets (<512 for k_bscan)
    const int nchunk = (E + CH - 1) / CH;    // 196 chunks (<= 64*KPL)

    char* ws = (char*)d_ws;
    auto alignup = [](size_t v) { return (v + 255) & ~(size_t)255; };
    size_t offb = 0;
    int*   hist = (int*)  (ws + offb); offb += alignup((size_t)nbv * nchunk * 4); // ~306 KB
    int*   bcnt = (int*)  (ws + offb); offb += alignup((size_t)(nbv + 1) * 4);
    int*   boff = (int*)  (ws + offb); offb += alignup((size_t)(nbv + 1) * 4);
    int*   off  = (int*)  (ws + offb); offb += alignup((size_t)(N + 1) * 4);
    float* dinv = (float*)(ws + offb); offb += alignup((size_t)N * 4);
    uint*  pairs= (uint*) (ws + offb); offb += alignup((size_t)E * 4);
    int*   srow = (int*)  (ws + offb); offb += alignup((size_t)E * 4);
    uint*  xws  = (uint*) (ws + offb); offb += alignup((size_t)N * HID * 2);
    uint*  hs   = (uint*) (ws + offb); offb += alignup((size_t)N * HID * 2);
    (void)ws_size; (void)n_in; (void)out_size;

    size_t histB = (size_t)nbv * 4;
    const int nxb = ((N / 16) + 3) / 4;      // k_xwm blocks (4 waves each)

    k_hist2<<<nchunk, 1024, histB,     stream>>>(col, hist, E, nbv, nchunk);
    k_cscan<<<(nbv + 3) / 4, 256, 0,   stream>>>(hist, bcnt, nchunk, nbv);
    k_bscan<<<1, 512, 0,               stream>>>(bcnt, boff, nbv, E);
    k_binW <<<nchunk, 1024, 2 * histB, stream>>>(row, col, hist, boff, pairs, E, nbv, nchunk);
    k_nsp  <<<nbv, 1024, 0,            stream>>>(pairs, boff, off, dinv, srow, N, nbv, E);
    k_xwm  <<<nxb, 256, 0,             stream>>>(x, W1, dinv, (__hip_bfloat16*)xws, N);
    k_agg1 <<<(N * 8 + 255) / 256, 256, 0, stream>>>(xws, off, srow, dinv, b1, hs, N);
    k_agg2 <<<(N * 8 + 255) / 256, 256, 0, stream>>>(hs, off, srow, dinv, W2, b2, out, N);
}